// Round 4
// baseline (268.930 us; speedup 1.0000x reference)
//
#include <hip/hip_runtime.h>
#include <stdint.h>

#define BB 32
#define AA 8400
#define CC 80
#define MM 64
#define KTOP 13
#define FEPS 1e-9f
#define CAND_CAP 1024   // max in-box anchors: 200*200/640^2 * 8400 ~= 820 worst mean

__device__ __forceinline__ float iou_fn(float gx1, float gy1, float gx2, float gy2,
                                        float px1, float py1, float px2, float py2) {
    float ix1 = fmaxf(gx1, px1), iy1 = fmaxf(gy1, py1);
    float ix2 = fminf(gx2, px2), iy2 = fminf(gy2, py2);
    float ov = fmaxf(ix2 - ix1, 0.0f) * fmaxf(iy2 - iy1, 0.0f);
    float a1 = fmaxf(gx2 - gx1, 0.0f) * fmaxf(gy2 - gy1, 0.0f);
    float a2 = fmaxf(px2 - px1, 0.0f) * fmaxf(py2 - py1, 0.0f);
    return ov / (a1 + a2 - ov + FEPS);
}

// Kernel 1: one block per (b,m). Cheap d-test filters ~97% of anchors; only
// in-box, positive-metric candidates (<1024, typ ~220) enter an LDS buffer.
// Then min(ncand,13) rounds of block-argmax with (value, lower-index) tie
// order == JAX top_k semantics, scattering bits directly into mask64.
// Correctness note vs reference: zero-metric / out-of-box top_k picks in the
// reference are always annihilated by the is_in_gts product in mask_positive,
// so restricting candidacy to d>EPS && metric>0 yields identical bits.
__global__ __launch_bounds__(256) void topk_scatter_kernel(
    const float* __restrict__ pred_scores, const float* __restrict__ pred_bboxes,
    const float* __restrict__ anchors, const int* __restrict__ gt_labels,
    const float* __restrict__ gt_bboxes, const float* __restrict__ pad_mask,
    unsigned long long* __restrict__ mask64)
{
    __shared__ float cv[CAND_CAP];
    __shared__ int   ci[CAND_CAP];
    __shared__ int   ncand_s;
    __shared__ float rv[4];
    __shared__ int   ri[4], rs[4];
    int bm = blockIdx.x;
    int t = threadIdx.x;
    if (t == 0) ncand_s = 0;
    __syncthreads();
    if (pad_mask[bm] == 0.0f) return;          // block-uniform exit

    int b = bm >> 6, m = bm & 63;
    float gx1 = gt_bboxes[bm * 4 + 0], gy1 = gt_bboxes[bm * 4 + 1];
    float gx2 = gt_bboxes[bm * 4 + 2], gy2 = gt_bboxes[bm * 4 + 3];
    float garea = (gx2 - gx1) * (gy2 - gy1);
    int lab = gt_labels[bm];
    const float* pb = pred_bboxes + (size_t)b * AA * 4;
    const float* ps = pred_scores + (size_t)b * AA * CC + lab;

    for (int a = t; a < AA; a += 256) {
        float2 xy = *(const float2*)(anchors + a * 2);
        float d = fminf(fminf(xy.x - gx1, xy.y - gy1), fminf(gx2 - xy.x, gy2 - xy.y));
        if (d > FEPS) {
            float4 p = *(const float4*)(pb + (size_t)a * 4);
            float s = ps[(size_t)a * CC];
            float ix1 = fmaxf(gx1, p.x), iy1 = fmaxf(gy1, p.y);
            float ix2 = fminf(gx2, p.z), iy2 = fminf(gy2, p.w);
            float ov = fmaxf(ix2 - ix1, 0.0f) * fmaxf(iy2 - iy1, 0.0f);
            float parea = (p.z - p.x) * (p.w - p.y);
            float iou = ov / (garea + parea - ov + FEPS);
            float i2 = iou * iou;
            float met = s * (i2 * i2 * i2);
            if (met > 0.0f) {
                int slot = atomicAdd(&ncand_s, 1);
                if (slot < CAND_CAP) { cv[slot] = met; ci[slot] = a; }
            }
        }
    }
    __syncthreads();
    int ncand = min(ncand_s, CAND_CAP);
    int rounds = min(ncand, KTOP);

    for (int k = 0; k < rounds; ++k) {
        float bv = -1.0f; int bi = 1 << 30, bs = -1;
        for (int i = t; i < ncand; i += 256) {
            float v = cv[i]; int idx = ci[i];
            if (v > bv || (v == bv && idx < bi)) { bv = v; bi = idx; bs = i; }
        }
        #pragma unroll
        for (int off = 32; off > 0; off >>= 1) {
            float ov = __shfl_xor(bv, off);
            int   oi = __shfl_xor(bi, off);
            int   os = __shfl_xor(bs, off);
            if (ov > bv || (ov == bv && oi < bi)) { bv = ov; bi = oi; bs = os; }
        }
        int lane = t & 63, wv = t >> 6;
        if (lane == 0) { rv[wv] = bv; ri[wv] = bi; rs[wv] = bs; }
        __syncthreads();
        if (t == 0) {
            float wbv = rv[0]; int wbi = ri[0], wbs = rs[0];
            #pragma unroll
            for (int w = 1; w < 4; ++w) {
                float ov = rv[w]; int oi = ri[w];
                if (ov > wbv || (ov == wbv && oi < wbi)) { wbv = ov; wbi = oi; wbs = rs[w]; }
            }
            cv[wbs] = -1.0f;   // metrics > 0: winner never re-picked
            atomicOr(&mask64[(size_t)b * AA + wbi], 1ull << m);
        }
        __syncthreads();
    }
}

// Kernel 2: per anchor — resolve multi-assignment via first-argmax of IoU over
// ALL m (incl. padded, as the reference does), write labels/bboxes, record
// assigned m + align, and atomicMax per-GT max_metrics / max_ious.
__global__ void resolve_kernel(
    const float* __restrict__ pred_scores, const float* __restrict__ pred_bboxes,
    const int* __restrict__ gt_labels, const float* __restrict__ gt_bboxes,
    const int* __restrict__ bg_ptr,
    const unsigned long long* __restrict__ mask64,
    float* __restrict__ out_labels, float* __restrict__ out_bboxes,
    int* __restrict__ assigned_m, float* __restrict__ assigned_align,
    unsigned int* __restrict__ maxmet, unsigned int* __restrict__ maxiou)
{
    int t = blockIdx.x * blockDim.x + threadIdx.x;
    if (t >= BB * AA) return;
    int b = t / AA;
    unsigned long long mask = mask64[t];
    int cnt = __popcll(mask);
    float4 p = *(const float4*)(pred_bboxes + (size_t)t * 4);
    int mstar = -1;
    if (cnt == 1) {
        mstar = __ffsll(mask) - 1;
    } else if (cnt > 1) {
        float best = -1.0f; int bi = 0;
        for (int m = 0; m < MM; ++m) {
            const float* g = gt_bboxes + (size_t)(b * MM + m) * 4;
            float iou = iou_fn(g[0], g[1], g[2], g[3], p.x, p.y, p.z, p.w);
            if (iou > best) { best = iou; bi = m; }   // strict > : first occurrence
        }
        mstar = bi;
    }
    assigned_m[t] = mstar;
    int bidx = (mstar >= 0) ? mstar : 0;   // argmax of all-zero column = 0
    const float* g = gt_bboxes + (size_t)(b * MM + bidx) * 4;
    float g0 = g[0], g1 = g[1], g2 = g[2], g3 = g[3];
    out_bboxes[(size_t)t * 4 + 0] = g0;
    out_bboxes[(size_t)t * 4 + 1] = g1;
    out_bboxes[(size_t)t * 4 + 2] = g2;
    out_bboxes[(size_t)t * 4 + 3] = g3;
    out_labels[t] = (mstar >= 0) ? (float)gt_labels[b * MM + mstar] : (float)(*bg_ptr);
    if (mstar >= 0) {
        float iou = iou_fn(g0, g1, g2, g3, p.x, p.y, p.z, p.w);
        int label = gt_labels[b * MM + mstar];
        int a = t % AA;
        float s = pred_scores[(size_t)b * AA * CC + (size_t)a * CC + label];
        float i2 = iou * iou;
        float al = s * (i2 * i2 * i2);
        assigned_align[t] = al;
        atomicMax(&maxmet[b * MM + mstar], __float_as_uint(al));
        atomicMax(&maxiou[b * MM + mstar], __float_as_uint(iou));
    }
}

// Kernel 3: write assigned_scores (B,A,80) as coalesced float4s.
__global__ void scores_kernel(
    const int* __restrict__ gt_labels,
    const int* __restrict__ assigned_m, const float* __restrict__ assigned_align,
    const unsigned int* __restrict__ maxmet, const unsigned int* __restrict__ maxiou,
    float* __restrict__ out_scores)
{
    int t = blockIdx.x * blockDim.x + threadIdx.x;
    if (t >= BB * AA * (CC / 4)) return;
    int anchor = t / (CC / 4); int j = t % (CC / 4);
    int m = assigned_m[anchor];
    float4 v = make_float4(0.0f, 0.0f, 0.0f, 0.0f);
    if (m >= 0) {
        int b = anchor / AA;
        int label = gt_labels[b * MM + m];
        int base = j * 4;
        if (label >= base && label < base + 4) {
            float mm = __uint_as_float(maxmet[b * MM + m]);
            float mi = __uint_as_float(maxiou[b * MM + m]);
            float scale = assigned_align[anchor] / (mm + FEPS) * mi;
            ((float*)&v)[label - base] = scale;
        }
    }
    *(float4*)(out_scores + (size_t)t * 4) = v;
}

extern "C" void kernel_launch(void* const* d_in, const int* in_sizes, int n_in,
                              void* d_out, int out_size, void* d_ws, size_t ws_size,
                              hipStream_t stream) {
    const float* pred_scores = (const float*)d_in[0];
    const float* pred_bboxes = (const float*)d_in[1];
    const float* anchors     = (const float*)d_in[2];
    const int*   gt_labels   = (const int*)d_in[3];
    const float* gt_bboxes   = (const float*)d_in[4];
    const float* pad_mask    = (const float*)d_in[5];
    const int*   bg_ptr      = (const int*)d_in[6];

    // Workspace layout. mask64 + maxmet + maxiou contiguous -> single memset.
    char* ws = (char*)d_ws;
    size_t off = 0;
    unsigned long long* mask64 = (unsigned long long*)(ws + off);   // B*A u64
    off += (size_t)BB * AA * sizeof(unsigned long long);
    unsigned int* maxmet  = (unsigned int*)(ws + off);  // B*M
    off += (size_t)BB * MM * sizeof(unsigned int);
    unsigned int* maxiou  = (unsigned int*)(ws + off);  // B*M
    off += (size_t)BB * MM * sizeof(unsigned int);
    size_t zero_bytes = off;
    int*   assigned_m     = (int*)(ws + off);           // B*A int
    off += (size_t)BB * AA * sizeof(int);
    float* assigned_align = (float*)(ws + off);         // B*A float
    off += (size_t)BB * AA * sizeof(float);

    hipMemsetAsync(ws, 0, zero_bytes, stream);

    float* out = (float*)d_out;
    float* out_labels = out;                         // B*A
    float* out_bboxes = out + (size_t)BB * AA;       // B*A*4
    float* out_scores = out + (size_t)BB * AA * 5;   // B*A*80

    topk_scatter_kernel<<<BB * MM, 256, 0, stream>>>(
        pred_scores, pred_bboxes, anchors, gt_labels, gt_bboxes, pad_mask, mask64);

    int n3 = BB * AA;
    resolve_kernel<<<(n3 + 255) / 256, 256, 0, stream>>>(
        pred_scores, pred_bboxes, gt_labels, gt_bboxes, bg_ptr, mask64,
        out_labels, out_bboxes, assigned_m, assigned_align, maxmet, maxiou);

    int n4 = BB * AA * (CC / 4);
    scores_kernel<<<(n4 + 255) / 256, 256, 0, stream>>>(
        gt_labels, assigned_m, assigned_align, maxmet, maxiou, out_scores);
}

// Round 6
// 264.352 us; speedup vs baseline: 1.0173x; 1.0173x over previous
//
#include <hip/hip_runtime.h>
#include <stdint.h>

#define BB 32
#define AA 8400
#define CC 80
#define MM 64
#define KTOP 13
#define FEPS 1e-9f
#define CAND_CAP 1024     // worst-case in-box anchors: Binom(8400, 0.0977) -> mean 820, sd 27
#define CNT_STRIDE 16     // pad counters to separate cache lines

typedef unsigned long long u64;

__device__ __forceinline__ float iou_fn(float gx1, float gy1, float gx2, float gy2,
                                        float px1, float py1, float px2, float py2) {
    float ix1 = fmaxf(gx1, px1), iy1 = fmaxf(gy1, py1);
    float ix2 = fminf(gx2, px2), iy2 = fminf(gy2, py2);
    float ov = fmaxf(ix2 - ix1, 0.0f) * fmaxf(iy2 - iy1, 0.0f);
    float a1 = fmaxf(gx2 - gx1, 0.0f) * fmaxf(gy2 - gy1, 0.0f);
    float a2 = fmaxf(px2 - px1, 0.0f) * fmaxf(py2 - py1, 0.0f);
    return ov / (a1 + a2 - ov + FEPS);
}

// Kernel A: one thread per (b, anchor). Dense 64-GT in-box test (uniform GT
// reads -> scalar loads), then sparse metric+push only for set bits (~1.7/anchor).
// Key pack: (float_bits(met)<<32) | (AA-a); met>0 so u64 max == (higher met,
// then lower anchor index) == JAX top_k tie semantics. Padded GTs excluded
// via ballot-built valid mask (reference: is_in_topk *= pad_gt_mask).
__global__ __launch_bounds__(256) void pairgen_kernel(
    const float* __restrict__ pred_scores, const float* __restrict__ pred_bboxes,
    const float* __restrict__ anchors, const int* __restrict__ gt_labels,
    const float* __restrict__ gt_bboxes, const float* __restrict__ pad_mask,
    int* __restrict__ cnt, u64* __restrict__ cand)
{
    __shared__ float4 gtb_s[MM];
    __shared__ int    gtl_s[MM];
    __shared__ u64    valid_s;
    int b = blockIdx.y;
    int t = threadIdx.x;
    if (t < MM) {
        gtb_s[t] = ((const float4*)gt_bboxes)[b * MM + t];
        gtl_s[t] = gt_labels[b * MM + t];
        bool v = pad_mask[b * MM + t] != 0.0f;
        u64 bal = __ballot(v);              // wave 0 covers exactly t=0..63
        if (t == 0) valid_s = bal;
    }
    __syncthreads();
    int a = blockIdx.x * 256 + t;
    if (a >= AA) return;
    float2 xy = *(const float2*)(anchors + a * 2);
    float4 p = ((const float4*)pred_bboxes)[(size_t)b * AA + a];
    const float4* gg = (const float4*)gt_bboxes + b * MM;   // uniform per iter
    u64 mask = 0;
    #pragma unroll 8
    for (int m = 0; m < MM; ++m) {
        float4 g = gg[m];
        float d = fminf(fminf(xy.x - g.x, xy.y - g.y), fminf(g.z - xy.x, g.w - xy.y));
        mask |= ((u64)(d > FEPS)) << m;
    }
    mask &= valid_s;
    if (!mask) return;
    float parea = (p.z - p.x) * (p.w - p.y);
    const float* psa = pred_scores + ((size_t)b * AA + a) * CC;
    unsigned ia = (unsigned)(AA - a);
    while (mask) {
        int m = __ffsll(mask) - 1;
        mask &= mask - 1;
        float4 g = gtb_s[m];                // divergent index -> LDS
        float ix1 = fmaxf(g.x, p.x), iy1 = fmaxf(g.y, p.y);
        float ix2 = fminf(g.z, p.z), iy2 = fminf(g.w, p.w);
        float ov = fmaxf(ix2 - ix1, 0.0f) * fmaxf(iy2 - iy1, 0.0f);
        float garea = (g.z - g.x) * (g.w - g.y);
        float iou = ov / (garea + parea - ov + FEPS);
        float s = psa[gtl_s[m]];
        float i2 = iou * iou;
        float met = s * (i2 * i2 * i2);
        if (met > 0.0f) {                   // always true in-box; cheap guard
            int bm = b * MM + m;
            int slot = atomicAdd(&cnt[bm * CNT_STRIDE], 1);
            if (slot < CAND_CAP)
                cand[(size_t)bm * CAND_CAP + slot] =
                    ((u64)__float_as_uint(met) << 32) | ia;
        }
    }
}

// Kernel B: per (b,m) block. <=1024 candidates -> 4 u64 regs/thread, 13 rounds
// of u64 block-max (keys unique: winner cleared by equality), scatter bit into
// per-anchor 64-bit assignment mask. Candidate-list order from atomicAdd is
// nondeterministic but the key max is order-invariant -> deterministic output.
__global__ __launch_bounds__(256) void select_scatter_kernel(
    const int* __restrict__ cnt, const u64* __restrict__ cand,
    u64* __restrict__ mask64)
{
    int bm = blockIdx.x;
    int n = min(cnt[bm * CNT_STRIDE], CAND_CAP);
    int rounds = min(n, KTOP);
    if (rounds == 0) return;                 // block-uniform (incl. padded GTs)
    int b = bm >> 6, m = bm & 63;
    int t = threadIdx.x;
    __shared__ u64 rv[2][4];
    u64 c[4];
    #pragma unroll
    for (int j = 0; j < 4; ++j) {
        int i = t + j * 256;
        c[j] = (i < n) ? cand[(size_t)bm * CAND_CAP + i] : 0;
    }
    int lane = t & 63, wv = t >> 6;
    for (int k = 0; k < rounds; ++k) {
        u64 bk = c[0];
        #pragma unroll
        for (int j = 1; j < 4; ++j) bk = (c[j] > bk) ? c[j] : bk;
        #pragma unroll
        for (int off = 32; off > 0; off >>= 1) {
            u64 ok = __shfl_xor(bk, off);
            bk = (ok > bk) ? ok : bk;
        }
        if (lane == 0) rv[k & 1][wv] = bk;
        __syncthreads();
        u64 wk = rv[k & 1][0];
        #pragma unroll
        for (int w = 1; w < 4; ++w) wk = (rv[k & 1][w] > wk) ? rv[k & 1][w] : wk;
        #pragma unroll
        for (int j = 0; j < 4; ++j) if (c[j] == wk) c[j] = 0;   // remove winner
        if (t == 0) {
            int a = AA - (int)(wk & 0xffffffffULL);
            atomicOr(&mask64[(size_t)b * AA + a], 1ull << m);
        }
    }
}

// Kernel C: per anchor — resolve multi-assignment via first-argmax of IoU over
// ALL m (incl. padded, as the reference does), write labels/bboxes, record
// assigned m + align, atomicMax per-GT max_metrics / max_ious.
__global__ __launch_bounds__(256) void resolve_kernel(
    const float* __restrict__ pred_scores, const float* __restrict__ pred_bboxes,
    const int* __restrict__ gt_labels, const float* __restrict__ gt_bboxes,
    const int* __restrict__ bg_ptr,
    const u64* __restrict__ mask64,
    float* __restrict__ out_labels, float* __restrict__ out_bboxes,
    int* __restrict__ assigned_m, float* __restrict__ assigned_align,
    unsigned int* __restrict__ maxmet, unsigned int* __restrict__ maxiou)
{
    __shared__ float4 gtb_s[MM];
    __shared__ int    gtl_s[MM];
    int b = blockIdx.y;
    int t = threadIdx.x;
    if (t < MM) {
        gtb_s[t] = ((const float4*)gt_bboxes)[b * MM + t];
        gtl_s[t] = gt_labels[b * MM + t];
    }
    __syncthreads();
    int a = blockIdx.x * 256 + t;
    if (a >= AA) return;
    size_t ga = (size_t)b * AA + a;
    u64 mask = mask64[ga];
    int cnt = __popcll(mask);
    float4 p = ((const float4*)pred_bboxes)[ga];
    int mstar = -1;
    if (cnt == 1) {
        mstar = __ffsll(mask) - 1;
    } else if (cnt > 1) {
        float best = -1.0f; int bi = 0;
        for (int m = 0; m < MM; ++m) {
            float4 g = gtb_s[m];
            float iou = iou_fn(g.x, g.y, g.z, g.w, p.x, p.y, p.z, p.w);
            if (iou > best) { best = iou; bi = m; }   // strict >: first occurrence
        }
        mstar = bi;
    }
    assigned_m[ga] = mstar;
    int bidx = (mstar >= 0) ? mstar : 0;   // argmax of all-zero column = 0
    float4 g = gtb_s[bidx];
    ((float4*)out_bboxes)[ga] = g;
    out_labels[ga] = (mstar >= 0) ? (float)gtl_s[mstar] : (float)(*bg_ptr);
    if (mstar >= 0) {
        float iou = iou_fn(g.x, g.y, g.z, g.w, p.x, p.y, p.z, p.w);
        float s = pred_scores[ga * CC + gtl_s[mstar]];
        float i2 = iou * iou;
        float al = s * (i2 * i2 * i2);
        assigned_align[ga] = al;
        atomicMax(&maxmet[b * MM + mstar], __float_as_uint(al));
        atomicMax(&maxiou[b * MM + mstar], __float_as_uint(iou));
    }
}

// Kernel D: write assigned_scores (B,A,80) as coalesced float4s.
__global__ __launch_bounds__(256) void scores_kernel(
    const int* __restrict__ gt_labels,
    const int* __restrict__ assigned_m, const float* __restrict__ assigned_align,
    const unsigned int* __restrict__ maxmet, const unsigned int* __restrict__ maxiou,
    float* __restrict__ out_scores)
{
    int t = blockIdx.x * blockDim.x + threadIdx.x;
    if (t >= BB * AA * (CC / 4)) return;
    int anchor = t / (CC / 4); int j = t % (CC / 4);
    int m = assigned_m[anchor];
    float4 v = make_float4(0.0f, 0.0f, 0.0f, 0.0f);
    if (m >= 0) {
        int b = anchor / AA;
        int label = gt_labels[b * MM + m];
        int base = j * 4;
        if (label >= base && label < base + 4) {
            float mm = __uint_as_float(maxmet[b * MM + m]);
            float mi = __uint_as_float(maxiou[b * MM + m]);
            float scale = assigned_align[anchor] / (mm + FEPS) * mi;
            ((float*)&v)[label - base] = scale;
        }
    }
    *(float4*)(out_scores + (size_t)t * 4) = v;
}

extern "C" void kernel_launch(void* const* d_in, const int* in_sizes, int n_in,
                              void* d_out, int out_size, void* d_ws, size_t ws_size,
                              hipStream_t stream) {
    const float* pred_scores = (const float*)d_in[0];
    const float* pred_bboxes = (const float*)d_in[1];
    const float* anchors     = (const float*)d_in[2];
    const int*   gt_labels   = (const int*)d_in[3];
    const float* gt_bboxes   = (const float*)d_in[4];
    const float* pad_mask    = (const float*)d_in[5];
    const int*   bg_ptr      = (const int*)d_in[6];

    // Workspace (~21 MB). Zeroed prefix: mask64 + cnt + maxmet + maxiou.
    char* ws = (char*)d_ws;
    size_t off = 0;
    u64* mask64 = (u64*)(ws + off);                        // B*A u64
    off += (size_t)BB * AA * sizeof(u64);
    int* cnt = (int*)(ws + off);                           // B*M padded counters
    off += (size_t)BB * MM * CNT_STRIDE * sizeof(int);
    unsigned int* maxmet = (unsigned int*)(ws + off);      // B*M
    off += (size_t)BB * MM * sizeof(unsigned int);
    unsigned int* maxiou = (unsigned int*)(ws + off);      // B*M
    off += (size_t)BB * MM * sizeof(unsigned int);
    size_t zero_bytes = off;
    u64* cand = (u64*)(ws + off);                          // B*M*1024 u64
    off += (size_t)BB * MM * CAND_CAP * sizeof(u64);
    int* assigned_m = (int*)(ws + off);                    // B*A
    off += (size_t)BB * AA * sizeof(int);
    float* assigned_align = (float*)(ws + off);            // B*A
    off += (size_t)BB * AA * sizeof(float);

    hipMemsetAsync(ws, 0, zero_bytes, stream);

    float* out = (float*)d_out;
    float* out_labels = out;                         // B*A
    float* out_bboxes = out + (size_t)BB * AA;       // B*A*4
    float* out_scores = out + (size_t)BB * AA * 5;   // B*A*80

    dim3 gridA((AA + 255) / 256, BB);
    pairgen_kernel<<<gridA, 256, 0, stream>>>(
        pred_scores, pred_bboxes, anchors, gt_labels, gt_bboxes, pad_mask,
        cnt, cand);

    select_scatter_kernel<<<BB * MM, 256, 0, stream>>>(cnt, cand, mask64);

    resolve_kernel<<<gridA, 256, 0, stream>>>(
        pred_scores, pred_bboxes, gt_labels, gt_bboxes, bg_ptr, mask64,
        out_labels, out_bboxes, assigned_m, assigned_align, maxmet, maxiou);

    int n4 = BB * AA * (CC / 4);
    scores_kernel<<<(n4 + 255) / 256, 256, 0, stream>>>(
        gt_labels, assigned_m, assigned_align, maxmet, maxiou, out_scores);
}